// Round 2
// baseline (691.801 us; speedup 1.0000x reference)
//
#include <hip/hip_runtime.h>

typedef unsigned short u16;
typedef unsigned int u32;
typedef __attribute__((ext_vector_type(8))) short bf16x8;
typedef __attribute__((ext_vector_type(4))) float f32x4;

#define T_TOK 2048
#define H_DIM 1024
#define E_NUM 8
#define F_DIM 2816
#define BM 64
#define BN 64
#define BK 32

__device__ __forceinline__ u16 f2bf(float f) {
    u32 b = __float_as_uint(f);
    u32 lsb = (b >> 16) & 1u;
    b += 0x7fffu + lsb;
    return (u16)(b >> 16);
}

// ---------------- Router: logits, softmax, top-2, bucket scatter --------------
__global__ __launch_bounds__(64) void router_kernel(
    const float* __restrict__ x, const float* __restrict__ gw,
    float* __restrict__ logits_out, int* __restrict__ cnt,
    int* __restrict__ tok_list, float* __restrict__ wt_list)
{
    int t = blockIdx.x;
    int lane = threadIdx.x;
    const float* xr = x + (size_t)t * H_DIM;

    float acc[E_NUM];
#pragma unroll
    for (int e = 0; e < E_NUM; e++) acc[e] = 0.f;

    for (int j = 0; j < H_DIM / 64; j++) {
        int idx = j * 64 + lane;
        float xv = xr[idx];
#pragma unroll
        for (int e = 0; e < E_NUM; e++)
            acc[e] += xv * gw[e * H_DIM + idx];
    }
#pragma unroll
    for (int e = 0; e < E_NUM; e++) {
        float v = acc[e];
#pragma unroll
        for (int o = 32; o > 0; o >>= 1) v += __shfl_xor(v, o, 64);
        acc[e] = v;
    }
    if (lane == 0) {
        // raw logits to output (fp32)
#pragma unroll
        for (int e = 0; e < E_NUM; e++) logits_out[t * E_NUM + e] = acc[e];
        // fp32 softmax
        float m = acc[0];
#pragma unroll
        for (int e = 1; e < E_NUM; e++) m = fmaxf(m, acc[e]);
        float p[E_NUM], s = 0.f;
#pragma unroll
        for (int e = 0; e < E_NUM; e++) { p[e] = expf(acc[e] - m); s += p[e]; }
        float inv = 1.f / s;
#pragma unroll
        for (int e = 0; e < E_NUM; e++) p[e] *= inv;
        // top-2 (lower index wins ties)
        int i0 = 0;
#pragma unroll
        for (int e = 1; e < E_NUM; e++) if (p[e] > p[i0]) i0 = e;
        int i1 = (i0 == 0) ? 1 : 0;
#pragma unroll
        for (int e = 0; e < E_NUM; e++) if (e != i0 && p[e] > p[i1]) i1 = e;
        float w0 = p[i0], w1 = p[i1];
        float rs = 1.f / (w0 + w1);
        w0 *= rs; w1 *= rs;
        int s0 = atomicAdd(&cnt[i0], 1);
        tok_list[i0 * T_TOK + s0] = t; wt_list[i0 * T_TOK + s0] = w0;
        int s1 = atomicAdd(&cnt[i1], 1);
        tok_list[i1 * T_TOK + s1] = t; wt_list[i1 * T_TOK + s1] = w1;
    }
}

// ---------------- Padded prefix offsets --------------------------------------
__global__ void offsets_kernel(const int* __restrict__ cnt, int* __restrict__ off)
{
    if (threadIdx.x == 0 && blockIdx.x == 0) {
        int s = 0;
        for (int e = 0; e < E_NUM; e++) {
            off[e] = s;
            s += ((cnt[e] + BM - 1) / BM) * BM;
        }
    }
}

// ---------------- GEMM1: act = silu(x*w1) * (x*w3) * wt ----------------------
__global__ __launch_bounds__(256) void gemm1_kernel(
    const float* __restrict__ x, const float* __restrict__ w1,
    const float* __restrict__ w3, const int* __restrict__ cnt,
    const int* __restrict__ off, const int* __restrict__ tok_list,
    const float* __restrict__ wt_list, u16* __restrict__ act)
{
    int e = blockIdx.z;
    int m0 = blockIdx.y * BM;
    int n0 = blockIdx.x * BN;
    int c = cnt[e];
    if (m0 >= c) return;

    __shared__ __align__(16) u16 As[BM][40];
    __shared__ __align__(16) u16 B1[BN][40];
    __shared__ __align__(16) u16 B3[BN][40];
    __shared__ int tok_s[BM];
    __shared__ float wt_s[BM];

    int tid = threadIdx.x;
    if (tid < BM) {
        int tok = tok_list[e * T_TOK + m0 + tid];
        tok_s[tid] = tok;
        wt_s[tid] = (tok >= 0) ? wt_list[e * T_TOK + m0 + tid] : 0.f;
    }
    __syncthreads();

    int w = tid >> 6, lane = tid & 63, q = lane >> 4, l15 = lane & 15;
    int wm = (w >> 1) * 32, wn = (w & 1) * 32;

    f32x4 zero = {0.f, 0.f, 0.f, 0.f};
    f32x4 accg[2][2], accu[2][2];
#pragma unroll
    for (int tm = 0; tm < 2; tm++)
#pragma unroll
        for (int tn = 0; tn < 2; tn++) { accg[tm][tn] = zero; accu[tm][tn] = zero; }

    // staging assignments
    int ar = tid >> 2, ac0 = (tid & 3) * 8;     // A: 64 rows x 32 cols (8 fp32/thread)
    int bk = tid >> 3, bf0 = (tid & 7) * 8;     // B: 32 k-rows x 64 f-cols (8 fp32/thread)
    int tokA = tok_s[ar];
    const size_t wbase = (size_t)e * H_DIM * F_DIM;

    for (int k0 = 0; k0 < H_DIM; k0 += BK) {
        // ---- A: fp32 -> bf16 convert -> LDS
        float a8[8];
#pragma unroll
        for (int i = 0; i < 8; i++) a8[i] = 0.f;
        if (tokA >= 0) {
            float4 v0 = *(const float4*)(x + (size_t)tokA * H_DIM + k0 + ac0);
            float4 v1 = *(const float4*)(x + (size_t)tokA * H_DIM + k0 + ac0 + 4);
            a8[0] = v0.x; a8[1] = v0.y; a8[2] = v0.z; a8[3] = v0.w;
            a8[4] = v1.x; a8[5] = v1.y; a8[6] = v1.z; a8[7] = v1.w;
        }
        union { uint4 v; u16 u[8]; } au;
#pragma unroll
        for (int i = 0; i < 8; i++) au.u[i] = f2bf(a8[i]);
        *(uint4*)&As[ar][ac0] = au.v;

        // ---- B1/B3: fp32 -> bf16 -> transposed LDS
        const size_t boff = wbase + (size_t)(k0 + bk) * F_DIM + n0 + bf0;
        float4 b1a = *(const float4*)(w1 + boff);
        float4 b1b = *(const float4*)(w1 + boff + 4);
        float4 b3a = *(const float4*)(w3 + boff);
        float4 b3b = *(const float4*)(w3 + boff + 4);
        float b1v[8] = {b1a.x, b1a.y, b1a.z, b1a.w, b1b.x, b1b.y, b1b.z, b1b.w};
        float b3v[8] = {b3a.x, b3a.y, b3a.z, b3a.w, b3b.x, b3b.y, b3b.z, b3b.w};
#pragma unroll
        for (int i = 0; i < 8; i++) {
            B1[bf0 + i][bk] = f2bf(b1v[i]);
            B3[bf0 + i][bk] = f2bf(b3v[i]);
        }
        __syncthreads();

        bf16x8 a[2], b1f[2], b3f[2];
#pragma unroll
        for (int tm = 0; tm < 2; tm++)
            a[tm] = *(const bf16x8*)&As[wm + tm * 16 + l15][q * 8];
#pragma unroll
        for (int tn = 0; tn < 2; tn++) {
            b1f[tn] = *(const bf16x8*)&B1[wn + tn * 16 + l15][q * 8];
            b3f[tn] = *(const bf16x8*)&B3[wn + tn * 16 + l15][q * 8];
        }
#pragma unroll
        for (int tm = 0; tm < 2; tm++)
#pragma unroll
            for (int tn = 0; tn < 2; tn++) {
                accg[tm][tn] = __builtin_amdgcn_mfma_f32_16x16x32_bf16(a[tm], b1f[tn], accg[tm][tn], 0, 0, 0);
                accu[tm][tn] = __builtin_amdgcn_mfma_f32_16x16x32_bf16(a[tm], b3f[tn], accu[tm][tn], 0, 0, 0);
            }
        __syncthreads();
    }

    int pos0 = off[e] + m0;
#pragma unroll
    for (int tm = 0; tm < 2; tm++)
#pragma unroll
        for (int tn = 0; tn < 2; tn++)
#pragma unroll
            for (int r = 0; r < 4; r++) {
                int row = wm + tm * 16 + q * 4 + r;
                float g = accg[tm][tn][r];
                float u = accu[tm][tn][r];
                float wt = wt_s[row];
                float sg = g / (1.f + expf(-g));
                float val = sg * u * wt;
                int col = n0 + wn + tn * 16 + l15;
                act[(size_t)(pos0 + row) * F_DIM + col] = f2bf(val);
            }
}

// ---------------- GEMM2: out += act * w2 (atomic fp32 scatter) ---------------
__global__ __launch_bounds__(256) void gemm2_kernel(
    const u16* __restrict__ act, const float* __restrict__ w2,
    const int* __restrict__ cnt, const int* __restrict__ off,
    const int* __restrict__ tok_list, float* __restrict__ accum)
{
    int e = blockIdx.z;
    int m0 = blockIdx.y * BM;
    int n0 = blockIdx.x * BN;
    int c = cnt[e];
    if (m0 >= c) return;

    __shared__ __align__(16) u16 As[BM][40];
    __shared__ __align__(16) u16 Bt[BN][40];
    __shared__ int tok_s[BM];

    int tid = threadIdx.x;
    if (tid < BM) tok_s[tid] = tok_list[e * T_TOK + m0 + tid];
    __syncthreads();

    int w = tid >> 6, lane = tid & 63, q = lane >> 4, l15 = lane & 15;
    int wm = (w >> 1) * 32, wn = (w & 1) * 32;

    f32x4 zero = {0.f, 0.f, 0.f, 0.f};
    f32x4 acc[2][2];
#pragma unroll
    for (int tm = 0; tm < 2; tm++)
#pragma unroll
        for (int tn = 0; tn < 2; tn++) acc[tm][tn] = zero;

    int ar = tid >> 2, ac0 = (tid & 3) * 8;
    int bk = tid >> 3, bf0 = (tid & 7) * 8;
    const size_t arow = (size_t)(off[e] + m0 + ar) * F_DIM;
    const size_t wbase = (size_t)e * F_DIM * H_DIM;

    for (int k0 = 0; k0 < F_DIM; k0 += BK) {
        // act is already bf16 in ws
        uint4 av = *(const uint4*)(act + arow + k0 + ac0);
        *(uint4*)&As[ar][ac0] = av;

        // w2: fp32 -> bf16 -> transposed LDS
        const size_t boff = wbase + (size_t)(k0 + bk) * H_DIM + n0 + bf0;
        float4 ba = *(const float4*)(w2 + boff);
        float4 bb = *(const float4*)(w2 + boff + 4);
        float bv[8] = {ba.x, ba.y, ba.z, ba.w, bb.x, bb.y, bb.z, bb.w};
#pragma unroll
        for (int i = 0; i < 8; i++) Bt[bf0 + i][bk] = f2bf(bv[i]);
        __syncthreads();

        bf16x8 a[2], b[2];
#pragma unroll
        for (int tm = 0; tm < 2; tm++)
            a[tm] = *(const bf16x8*)&As[wm + tm * 16 + l15][q * 8];
#pragma unroll
        for (int tn = 0; tn < 2; tn++)
            b[tn] = *(const bf16x8*)&Bt[wn + tn * 16 + l15][q * 8];
#pragma unroll
        for (int tm = 0; tm < 2; tm++)
#pragma unroll
            for (int tn = 0; tn < 2; tn++)
                acc[tm][tn] = __builtin_amdgcn_mfma_f32_16x16x32_bf16(a[tm], b[tn], acc[tm][tn], 0, 0, 0);
        __syncthreads();
    }

#pragma unroll
    for (int tm = 0; tm < 2; tm++)
#pragma unroll
        for (int tn = 0; tn < 2; tn++)
#pragma unroll
            for (int r = 0; r < 4; r++) {
                int row = wm + tm * 16 + q * 4 + r;
                int tok = tok_s[row];
                if (tok >= 0) {
                    int col = n0 + wn + tn * 16 + l15;
                    atomicAdd(&accum[(size_t)tok * H_DIM + col], acc[tm][tn][r]);
                }
            }
}

// ---------------- fp32 accum -> fp32 out -------------------------------------
__global__ __launch_bounds__(256) void conv_kernel(
    const float* __restrict__ accum, float* __restrict__ out)
{
    int i = blockIdx.x * 256 + threadIdx.x;
    out[i] = accum[i];
}

extern "C" void kernel_launch(void* const* d_in, const int* in_sizes, int n_in,
                              void* d_out, int out_size, void* d_ws, size_t ws_size,
                              hipStream_t stream) {
    const float* x  = (const float*)d_in[0];
    const float* gw = (const float*)d_in[1];
    const float* w1 = (const float*)d_in[2];
    const float* w3 = (const float*)d_in[3];
    const float* w2 = (const float*)d_in[4];
    float* out = (float*)d_out;

    char* ws = (char*)d_ws;
    int*   cnt      = (int*)(ws);                                  // 32 B
    int*   off      = (int*)(ws + 64);                             // 32 B
    int*   tok_list = (int*)(ws + 128);                            // 64 KiB
    float* wt_list  = (float*)(ws + 128 + 65536);                  // 64 KiB
    float* accum    = (float*)(ws + 128 + 131072);                 // 8 MiB
    u16*   act      = (u16*)(ws + 128 + 131072 + 8388608);         // ~26 MiB (bf16)

    hipMemsetAsync(cnt, 0, 64, stream);
    hipMemsetAsync(tok_list, 0xFF, 65536, stream);
    hipMemsetAsync(accum, 0, (size_t)T_TOK * H_DIM * 4, stream);

    float* logits_out = out + (size_t)T_TOK * H_DIM;
    router_kernel<<<T_TOK, 64, 0, stream>>>(x, gw, logits_out, cnt, tok_list, wt_list);
    offsets_kernel<<<1, 64, 0, stream>>>(cnt, off);
    gemm1_kernel<<<dim3(F_DIM / BN, T_TOK / BM, E_NUM), 256, 0, stream>>>(
        x, w1, w3, cnt, off, tok_list, wt_list, act);
    gemm2_kernel<<<dim3(H_DIM / BN, T_TOK / BM, E_NUM), 256, 0, stream>>>(
        act, w2, cnt, off, tok_list, accum);
    conv_kernel<<<(T_TOK * H_DIM) / 256, 256, 0, stream>>>(accum, out);
}